// Round 11
// baseline (445.676 us; speedup 1.0000x reference)
//
#include <hip/hip_runtime.h>
#include <hip/hip_bf16.h>

#define N_NODES 50000
#define DIM 128
#define N_EDGES 800000
#define NEG_SLOPE 0.2f
#define LN_EPS 1e-5f
#define PADCAP (N_EDGES + 7 * N_NODES)   // >= sum(ceil8(deg))
#define SCAN_T 1024
#define ITEMS ((N_NODES + SCAN_T - 1) / SCAN_T)   // 49
#define LINPAD 20

// Workspace (~31.4 MB, proven ws >= 35.8 MB):
//   xl_bf     : N*D bf16      (12.8 MB)
//   packed    : PADCAP float4 (18.4 MB) {ea0,ea1,ea2,src_bits} dst-sorted, rows 8-aligned
//   row_start : N int   (hist counts -> padded exclusive scan)
//   cursor    : N int   (scatter cursor -> real row end)
// x_r (f32) parked in d_out rows until fused kernel overwrites them.

__device__ __forceinline__ unsigned short f2bf(float f) {
    __hip_bfloat16 h = __float2bfloat16(f);
    return *reinterpret_cast<unsigned short*>(&h);
}

// K1: xl = bf16(x@W_l+b_l) -> ws ; xr = x@W_r+b_r -> d_out.
// 16 nodes/block, 256 threads; thread tile = 4 nodes x 4 cols; x staged
// transposed in LDS so compute reads are ds_read_b128.
__global__ __launch_bounds__(256) void lin_kernel(
    const float* __restrict__ x,
    const float* __restrict__ Wl, const float* __restrict__ bl,
    const float* __restrict__ Wr, const float* __restrict__ br,
    __hip_bfloat16* __restrict__ xl_bf, float* __restrict__ xr)
{
    __shared__ float xs[DIM][LINPAD];   // [k][node], pad 20: 16B-aligned rows
    const int node0 = blockIdx.x * 16;
    const int t = threadIdx.x;
    for (int idx = t; idx < 16 * DIM; idx += 256) {
        const int n = idx >> 7, k = idx & 127;
        const int gn = node0 + n;
        xs[k][n] = (gn < N_NODES) ? x[(size_t)gn * DIM + k] : 0.f;
    }
    __syncthreads();
    const int tn = (t & 3) * 4;          // nodes tn..tn+3
    const int tc = (t >> 2) * 4;         // cols tc..tc+3 of [Wl|Wr]
    const bool is_l = tc < DIM;
    const float* W = is_l ? Wl : Wr;
    const float* b = is_l ? bl : br;
    const int col = is_l ? tc : tc - DIM;
    float4 a0 = {0.f, 0.f, 0.f, 0.f}, a1 = a0, a2 = a0, a3 = a0;
#pragma unroll 4
    for (int k = 0; k < DIM; ++k) {
        const float4 wv = *(const float4*)&W[k * DIM + col];
        const float4 xv = *(const float4*)&xs[k][tn];
        a0.x += xv.x * wv.x; a0.y += xv.x * wv.y; a0.z += xv.x * wv.z; a0.w += xv.x * wv.w;
        a1.x += xv.y * wv.x; a1.y += xv.y * wv.y; a1.z += xv.y * wv.z; a1.w += xv.y * wv.w;
        a2.x += xv.z * wv.x; a2.y += xv.z * wv.y; a2.z += xv.z * wv.z; a2.w += xv.z * wv.w;
        a3.x += xv.w * wv.x; a3.y += xv.w * wv.y; a3.z += xv.w * wv.z; a3.w += xv.w * wv.w;
    }
    const float4 bv = *(const float4*)&b[col];
    a0.x += bv.x; a0.y += bv.y; a0.z += bv.z; a0.w += bv.w;
    a1.x += bv.x; a1.y += bv.y; a1.z += bv.z; a1.w += bv.w;
    a2.x += bv.x; a2.y += bv.y; a2.z += bv.z; a2.w += bv.w;
    a3.x += bv.x; a3.y += bv.y; a3.z += bv.z; a3.w += bv.w;
    float4 acc[4] = {a0, a1, a2, a3};
#pragma unroll
    for (int i = 0; i < 4; ++i) {
        const int gn = node0 + tn + i;
        if (gn >= N_NODES) continue;
        if (is_l) {
            ushort4 u;
            u.x = f2bf(acc[i].x); u.y = f2bf(acc[i].y);
            u.z = f2bf(acc[i].z); u.w = f2bf(acc[i].w);
            *(ushort4*)&xl_bf[(size_t)gn * DIM + col] = u;
        } else {
            *(float4*)&xr[(size_t)gn * DIM + col] = acc[i];
        }
    }
}

// ---------------- CSR build ----------------
__global__ __launch_bounds__(256) void hist_kernel(const int* __restrict__ dst_idx,
                                                   int* __restrict__ cnt) {
    int i = blockIdx.x * 256 + threadIdx.x;
    int e = i * 4;
    if (e + 4 <= N_EDGES) {
        const int4 d4 = *(const int4*)(dst_idx + e);
        atomicAdd(&cnt[d4.x], 1);
        atomicAdd(&cnt[d4.y], 1);
        atomicAdd(&cnt[d4.z], 1);
        atomicAdd(&cnt[d4.w], 1);
    } else {
        for (; e < N_EDGES; ++e) atomicAdd(&cnt[dst_idx[e]], 1);
    }
}

// single-kernel padded exclusive scan: 1 block, 1024 threads, 49 nodes each.
__global__ __launch_bounds__(SCAN_T) void scan_all_kernel(int* __restrict__ cnt,
                                                          int* __restrict__ cursor) {
    __shared__ int sh[SCAN_T];
    const int t = threadIdx.x;
    const int i0 = t * ITEMS;
    const int i1 = (i0 + ITEMS < N_NODES) ? i0 + ITEMS : N_NODES;
    int sum = 0;
    for (int i = i0; i < i1; ++i) sum += (cnt[i] + 7) & ~7;
    sh[t] = sum;
    __syncthreads();
    for (int off = 1; off < SCAN_T; off <<= 1) {
        int u = (t >= off) ? sh[t - off] : 0;
        __syncthreads();
        sh[t] += u;
        __syncthreads();
    }
    int run = (t == 0) ? 0 : sh[t - 1];
    for (int i = i0; i < i1; ++i) {
        const int pad = (cnt[i] + 7) & ~7;
        cnt[i] = run;       // row_start (multiple of 8)
        cursor[i] = run;    // scatter cursor; becomes real row end
        run += pad;
    }
}

// scatter: ONE aligned 16B store per edge: {ea0, ea1, ea2, bitcast(src)}
__global__ __launch_bounds__(256) void scatter_kernel(
    const int* __restrict__ src_idx, const int* __restrict__ dst_idx,
    const float* __restrict__ ea,
    int* __restrict__ cursor, float4* __restrict__ packed) {
    int e = blockIdx.x * 256 + threadIdx.x;
    if (e >= N_EDGES) return;
    int pos = atomicAdd(&cursor[dst_idx[e]], 1);
    float4 p;
    p.x = ea[(size_t)e * 3 + 0];
    p.y = ea[(size_t)e * 3 + 1];
    p.z = ea[(size_t)e * 3 + 2];
    p.w = __int_as_float(src_idx[e]);
    packed[pos] = p;
}

// per-edge logit from decoded xl + constants (2 dims per lane)
#define LOGIT(PX, K, XL0, XL1)                                               \
    {                                                                        \
        float t0 = (XL0) + xrv.x + (K).x * we0.x + (K).y * we1.x + (K).z * we2.x; \
        float t1 = (XL1) + xrv.y + (K).x * we0.y + (K).y * we1.y + (K).z * we2.y; \
        t0 = t0 > 0.f ? t0 : NEG_SLOPE * t0;                                 \
        t1 = t1 > 0.f ? t1 : NEG_SLOPE * t1;                                 \
        PX = t0 * at.x + t1 * at.y;                                          \
    }

// K_F: one wave per 4 consecutive nodes; constants hoisted; 8 edges/iter
// straight-line; interleaved butterfly; deferred-max online softmax; fused LN.
__global__ __launch_bounds__(256) void fused_node_kernel(
    const float* __restrict__ x, const __hip_bfloat16* __restrict__ xl_bf,
    const int* __restrict__ row_start, const int* __restrict__ cursor,
    const float4* __restrict__ packed,
    const float* __restrict__ We, const float* __restrict__ att,
    const float* __restrict__ bias, const float* __restrict__ rw_p,
    const float* __restrict__ gamma, const float* __restrict__ beta,
    float* __restrict__ out)
{
    const int wave = blockIdx.x * 4 + (threadIdx.x >> 6);
    const int lane = threadIdx.x & 63;
    const int v0 = wave * 4;
    if (v0 >= N_NODES) return;
    const int loff = 2 * lane;
    // node-invariant constants (once per wave, amortized over 4 nodes)
    const float2 at  = *(const float2*)&att[loff];
    const float2 we0 = *(const float2*)&We[0 * DIM + loff];
    const float2 we1 = *(const float2*)&We[1 * DIM + loff];
    const float2 we2 = *(const float2*)&We[2 * DIM + loff];
    const float2 bi  = *(const float2*)&bias[loff];
    const float2 gm  = *(const float2*)&gamma[loff];
    const float2 bt  = *(const float2*)&beta[loff];
    const float rw = rw_p[0];

    for (int j = 0; j < 4; ++j) {
        const int v = v0 + j;
        if (v >= N_NODES) return;
        const int begin = row_start[v];      // %8 == 0
        const int end   = cursor[v];         // begin + deg
        const size_t nb = (size_t)v * DIM + loff;
        const float2 xrv = *(const float2*)&out[nb];   // x_r row (parked)

        float m = -3.4e38f, s = 0.f, a0 = 0.f, a1 = 0.f;
        int pos = begin;
        const int full8 = begin + ((end - begin) & ~7);

        for (; pos < full8; pos += 8) {
            const float4 k0 = packed[pos + 0], k1 = packed[pos + 1];
            const float4 k2 = packed[pos + 2], k3 = packed[pos + 3];
            const float4 k4 = packed[pos + 4], k5 = packed[pos + 5];
            const float4 k6 = packed[pos + 6], k7 = packed[pos + 7];
            const unsigned xu0 = *(const unsigned*)&xl_bf[(size_t)__float_as_int(k0.w) * DIM + loff];
            const unsigned xu1 = *(const unsigned*)&xl_bf[(size_t)__float_as_int(k1.w) * DIM + loff];
            const unsigned xu2 = *(const unsigned*)&xl_bf[(size_t)__float_as_int(k2.w) * DIM + loff];
            const unsigned xu3 = *(const unsigned*)&xl_bf[(size_t)__float_as_int(k3.w) * DIM + loff];
            const unsigned xu4 = *(const unsigned*)&xl_bf[(size_t)__float_as_int(k4.w) * DIM + loff];
            const unsigned xu5 = *(const unsigned*)&xl_bf[(size_t)__float_as_int(k5.w) * DIM + loff];
            const unsigned xu6 = *(const unsigned*)&xl_bf[(size_t)__float_as_int(k6.w) * DIM + loff];
            const unsigned xu7 = *(const unsigned*)&xl_bf[(size_t)__float_as_int(k7.w) * DIM + loff];
            const float xl00 = __uint_as_float(xu0 << 16), xl10 = __uint_as_float(xu0 & 0xffff0000u);
            const float xl01 = __uint_as_float(xu1 << 16), xl11 = __uint_as_float(xu1 & 0xffff0000u);
            const float xl02 = __uint_as_float(xu2 << 16), xl12 = __uint_as_float(xu2 & 0xffff0000u);
            const float xl03 = __uint_as_float(xu3 << 16), xl13 = __uint_as_float(xu3 & 0xffff0000u);
            const float xl04 = __uint_as_float(xu4 << 16), xl14 = __uint_as_float(xu4 & 0xffff0000u);
            const float xl05 = __uint_as_float(xu5 << 16), xl15 = __uint_as_float(xu5 & 0xffff0000u);
            const float xl06 = __uint_as_float(xu6 << 16), xl16 = __uint_as_float(xu6 & 0xffff0000u);
            const float xl07 = __uint_as_float(xu7 << 16), xl17 = __uint_as_float(xu7 & 0xffff0000u);

            float P0, P1, P2, P3, P4, P5, P6, P7;
            LOGIT(P0, k0, xl00, xl10)  LOGIT(P1, k1, xl01, xl11)
            LOGIT(P2, k2, xl02, xl12)  LOGIT(P3, k3, xl03, xl13)
            LOGIT(P4, k4, xl04, xl14)  LOGIT(P5, k5, xl05, xl15)
            LOGIT(P6, k6, xl06, xl16)  LOGIT(P7, k7, xl07, xl17)

            const bool b1 = (lane & 1), b2 = (lane & 2), b4 = (lane & 4);
            float A0, A1, A2, A3, B0, B1, G;
            {
                const float q0 = __shfl_xor(P0, 1, 64), q1 = __shfl_xor(P1, 1, 64);
                const float q2 = __shfl_xor(P2, 1, 64), q3 = __shfl_xor(P3, 1, 64);
                const float q4 = __shfl_xor(P4, 1, 64), q5 = __shfl_xor(P5, 1, 64);
                const float q6 = __shfl_xor(P6, 1, 64), q7 = __shfl_xor(P7, 1, 64);
                A0 = b1 ? (P1 + q1) : (P0 + q0);
                A1 = b1 ? (P3 + q3) : (P2 + q2);
                A2 = b1 ? (P5 + q5) : (P4 + q4);
                A3 = b1 ? (P7 + q7) : (P6 + q6);
            }
            {
                const float q0 = __shfl_xor(A0, 2, 64), q1 = __shfl_xor(A1, 2, 64);
                const float q2 = __shfl_xor(A2, 2, 64), q3 = __shfl_xor(A3, 2, 64);
                B0 = b2 ? (A1 + q1) : (A0 + q0);
                B1 = b2 ? (A3 + q3) : (A2 + q2);
            }
            {
                const float q0 = __shfl_xor(B0, 4, 64), q1 = __shfl_xor(B1, 4, 64);
                G = b4 ? (B1 + q1) : (B0 + q0);
            }
            G += __shfl_xor(G, 8, 64);
            G += __shfl_xor(G, 16, 64);
            G += __shfl_xor(G, 32, 64);
            const float p0 = __shfl(G, 0, 64), p1 = __shfl(G, 1, 64);
            const float p2 = __shfl(G, 2, 64), p3 = __shfl(G, 3, 64);
            const float p4 = __shfl(G, 4, 64), p5 = __shfl(G, 5, 64);
            const float p6 = __shfl(G, 6, 64), p7 = __shfl(G, 7, 64);

            const float pm = fmaxf(fmaxf(fmaxf(p0, p1), fmaxf(p2, p3)),
                                   fmaxf(fmaxf(p4, p5), fmaxf(p6, p7)));
            if (pm <= m + 8.f) {
                const float w0 = __expf(p0 - m), w1 = __expf(p1 - m);
                const float w2 = __expf(p2 - m), w3 = __expf(p3 - m);
                const float w4 = __expf(p4 - m), w5 = __expf(p5 - m);
                const float w6 = __expf(p6 - m), w7 = __expf(p7 - m);
                s  += ((w0 + w1) + (w2 + w3)) + ((w4 + w5) + (w6 + w7));
                a0 += (w0 * xl00 + w1 * xl01 + w2 * xl02 + w3 * xl03)
                    + (w4 * xl04 + w5 * xl05 + w6 * xl06 + w7 * xl07);
                a1 += (w0 * xl10 + w1 * xl11 + w2 * xl12 + w3 * xl13)
                    + (w4 * xl14 + w5 * xl15 + w6 * xl16 + w7 * xl17);
            } else {
                const float mn = fmaxf(m, pm);
                const float f  = __expf(m - mn);
                const float w0 = __expf(p0 - mn), w1 = __expf(p1 - mn);
                const float w2 = __expf(p2 - mn), w3 = __expf(p3 - mn);
                const float w4 = __expf(p4 - mn), w5 = __expf(p5 - mn);
                const float w6 = __expf(p6 - mn), w7 = __expf(p7 - mn);
                s  = s  * f + ((w0 + w1) + (w2 + w3)) + ((w4 + w5) + (w6 + w7));
                a0 = a0 * f + (w0 * xl00 + w1 * xl01 + w2 * xl02 + w3 * xl03)
                            + (w4 * xl04 + w5 * xl05 + w6 * xl06 + w7 * xl07);
                a1 = a1 * f + (w0 * xl10 + w1 * xl11 + w2 * xl12 + w3 * xl13)
                            + (w4 * xl14 + w5 * xl15 + w6 * xl16 + w7 * xl17);
                m = mn;
            }
        }

        if (end - pos >= 4) {
            const float4 k0 = packed[pos + 0], k1 = packed[pos + 1];
            const float4 k2 = packed[pos + 2], k3 = packed[pos + 3];
            const unsigned xu0 = *(const unsigned*)&xl_bf[(size_t)__float_as_int(k0.w) * DIM + loff];
            const unsigned xu1 = *(const unsigned*)&xl_bf[(size_t)__float_as_int(k1.w) * DIM + loff];
            const unsigned xu2 = *(const unsigned*)&xl_bf[(size_t)__float_as_int(k2.w) * DIM + loff];
            const unsigned xu3 = *(const unsigned*)&xl_bf[(size_t)__float_as_int(k3.w) * DIM + loff];
            const float xl00 = __uint_as_float(xu0 << 16), xl10 = __uint_as_float(xu0 & 0xffff0000u);
            const float xl01 = __uint_as_float(xu1 << 16), xl11 = __uint_as_float(xu1 & 0xffff0000u);
            const float xl02 = __uint_as_float(xu2 << 16), xl12 = __uint_as_float(xu2 & 0xffff0000u);
            const float xl03 = __uint_as_float(xu3 << 16), xl13 = __uint_as_float(xu3 & 0xffff0000u);
            float P0, P1, P2, P3;
            LOGIT(P0, k0, xl00, xl10)  LOGIT(P1, k1, xl01, xl11)
            LOGIT(P2, k2, xl02, xl12)  LOGIT(P3, k3, xl03, xl13)
            const float tA0 = __shfl_xor(P0, 1, 64), tA1 = __shfl_xor(P1, 1, 64);
            const float tB0 = __shfl_xor(P2, 1, 64), tB1 = __shfl_xor(P3, 1, 64);
            const bool b0 = (lane & 1);
            float A = b0 ? (P1 + tA1) : (P0 + tA0);
            float B = b0 ? (P3 + tB1) : (P2 + tB0);
            const float tA = __shfl_xor(A, 2, 64), tB = __shfl_xor(B, 2, 64);
            float C = (lane & 2) ? (B + tB) : (A + tA);
            C += __shfl_xor(C, 4, 64);
            C += __shfl_xor(C, 8, 64);
            C += __shfl_xor(C, 16, 64);
            C += __shfl_xor(C, 32, 64);
            const float p0 = __shfl(C, 0, 64), p1 = __shfl(C, 1, 64);
            const float p2 = __shfl(C, 2, 64), p3 = __shfl(C, 3, 64);
            const float pm = fmaxf(fmaxf(p0, p1), fmaxf(p2, p3));
            if (pm <= m + 8.f) {
                const float w0 = __expf(p0 - m), w1 = __expf(p1 - m);
                const float w2 = __expf(p2 - m), w3 = __expf(p3 - m);
                s  += (w0 + w1) + (w2 + w3);
                a0 += w0 * xl00 + w1 * xl01 + w2 * xl02 + w3 * xl03;
                a1 += w0 * xl10 + w1 * xl11 + w2 * xl12 + w3 * xl13;
            } else {
                const float mn = fmaxf(m, pm);
                const float f  = __expf(m - mn);
                const float w0 = __expf(p0 - mn), w1 = __expf(p1 - mn);
                const float w2 = __expf(p2 - mn), w3 = __expf(p3 - mn);
                s  = s  * f + (w0 + w1) + (w2 + w3);
                a0 = a0 * f + w0 * xl00 + w1 * xl01 + w2 * xl02 + w3 * xl03;
                a1 = a1 * f + w0 * xl10 + w1 * xl11 + w2 * xl12 + w3 * xl13;
                m = mn;
            }
            pos += 4;
        }

        for (; pos < end; ++pos) {
            const float4 pk = packed[pos];
            const unsigned xu = *(const unsigned*)&xl_bf[(size_t)__float_as_int(pk.w) * DIM + loff];
            const float xl0 = __uint_as_float(xu << 16);
            const float xl1 = __uint_as_float(xu & 0xffff0000u);
            float p;
            LOGIT(p, pk, xl0, xl1)
#pragma unroll
            for (int o = 32; o > 0; o >>= 1) p += __shfl_xor(p, o, 64);
            if (p <= m + 8.f) {
                const float w = __expf(p - m);
                s += w; a0 += w * xl0; a1 += w * xl1;
            } else {
                const float mn = fmaxf(m, p);
                const float f = __expf(m - mn);
                const float w = __expf(p - mn);
                s = s * f + w; a0 = a0 * f + w * xl0; a1 = a1 * f + w * xl1;
                m = mn;
            }
        }

        const float inv = 1.f / (s + 1e-16f);

        // epilogue: residual + LayerNorm
        const float2 xv = *(const float2*)&x[nb];
        float u0 = xv.x + rw * (a0 * inv + bi.x);
        float u1 = xv.y + rw * (a1 * inv + bi.y);
        float sum = u0 + u1;
#pragma unroll
        for (int o = 32; o > 0; o >>= 1) sum += __shfl_xor(sum, o, 64);
        const float mu = sum * (1.f / DIM);
        const float d0 = u0 - mu, d1 = u1 - mu;
        float q = d0 * d0 + d1 * d1;
#pragma unroll
        for (int o = 32; o > 0; o >>= 1) q += __shfl_xor(q, o, 64);
        const float rstd = rsqrtf(q * (1.f / DIM) + LN_EPS);
        float2 r;
        r.x = d0 * rstd * gm.x + bt.x;
        r.y = d1 * rstd * gm.y + bt.y;
        *(float2*)&out[nb] = r;
    }
}

extern "C" void kernel_launch(void* const* d_in, const int* in_sizes, int n_in,
                              void* d_out, int out_size, void* d_ws, size_t ws_size,
                              hipStream_t stream)
{
    const float* x    = (const float*)d_in[0];
    const int*   ei   = (const int*)d_in[1];
    const float* ea   = (const float*)d_in[2];
    const float* Wl   = (const float*)d_in[3];
    const float* bl   = (const float*)d_in[4];
    const float* Wr   = (const float*)d_in[5];
    const float* br   = (const float*)d_in[6];
    const float* We   = (const float*)d_in[7];
    const float* att  = (const float*)d_in[8];
    const float* bias = (const float*)d_in[9];
    const float* rw   = (const float*)d_in[10];
    const float* gmm  = (const float*)d_in[11];
    const float* bta  = (const float*)d_in[12];
    float* out = (float*)d_out;

    const int* src_idx = ei;            // edge_index[0]
    const int* dst_idx = ei + N_EDGES;  // edge_index[1]

    __hip_bfloat16* xl_bf = (__hip_bfloat16*)d_ws;                 // N*D bf16
    float4* packed    = (float4*)(xl_bf + (size_t)N_NODES * DIM);  // PADCAP
    int*   row_start  = (int*)(packed + PADCAP);                   // N
    int*   cursor     = row_start + N_NODES;                       // N

    hipMemsetAsync(row_start, 0, (size_t)N_NODES * sizeof(int), stream);
    hist_kernel<<<(N_EDGES / 4 + 255) / 256, 256, 0, stream>>>(dst_idx, row_start);
    scan_all_kernel<<<1, SCAN_T, 0, stream>>>(row_start, cursor);
    scatter_kernel<<<(N_EDGES + 255) / 256, 256, 0, stream>>>(src_idx, dst_idx, ea,
                                                              cursor, packed);
    lin_kernel<<<(N_NODES + 15) / 16, 256, 0, stream>>>(x, Wl, bl, Wr, br, xl_bf, out);
    fused_node_kernel<<<(N_NODES + 15) / 16, 256, 0, stream>>>(x, xl_bf, row_start, cursor,
                                                               packed,
                                                               We, att, bias, rw, gmm, bta, out);
}

// Round 12
// 346.434 us; speedup vs baseline: 1.2865x; 1.2865x over previous
//
#include <hip/hip_runtime.h>
#include <hip/hip_bf16.h>

#define N_NODES 50000
#define DIM 128
#define N_EDGES 800000
#define NEG_SLOPE 0.2f
#define LN_EPS 1e-5f
#define SCAN_BS 256
#define NB_SCAN ((N_NODES + SCAN_BS - 1) / SCAN_BS)   // 196
#define PADCAP (N_EDGES + 7 * N_NODES)   // >= sum(ceil8(deg))
#define LINPAD 20

// Workspace (~31.4 MB):
//   xl_bf     : N*D bf16      (12.8 MB)
//   packed    : PADCAP float4 (18.4 MB) {ea0,ea1,ea2,src_bits} dst-sorted, rows 8-aligned
//   row_start : N int
//   cursor    : N int
//   partials  : 256 int
// x_r (f32) parked in d_out rows until fused kernel overwrites them.

__device__ __forceinline__ unsigned short f2bf(float f) {
    __hip_bfloat16 h = __float2bfloat16(f);
    return *reinterpret_cast<unsigned short*>(&h);
}

// K1: xl = bf16(x@W_l+b_l) -> ws ; xr = x@W_r+b_r -> d_out.
// 16 nodes/block, 256 threads; thread tile = 4 nodes x 4 cols; x staged
// transposed in LDS so compute reads are ds_read_b128.
__global__ __launch_bounds__(256) void lin_kernel(
    const float* __restrict__ x,
    const float* __restrict__ Wl, const float* __restrict__ bl,
    const float* __restrict__ Wr, const float* __restrict__ br,
    __hip_bfloat16* __restrict__ xl_bf, float* __restrict__ xr)
{
    __shared__ float xs[DIM][LINPAD];   // [k][node], pad 20: 16B-aligned rows
    const int node0 = blockIdx.x * 16;
    const int t = threadIdx.x;
    for (int idx = t; idx < 16 * DIM; idx += 256) {
        const int n = idx >> 7, k = idx & 127;
        const int gn = node0 + n;
        xs[k][n] = (gn < N_NODES) ? x[(size_t)gn * DIM + k] : 0.f;
    }
    __syncthreads();
    const int tn = (t & 3) * 4;          // nodes tn..tn+3
    const int tc = (t >> 2) * 4;         // cols tc..tc+3 of [Wl|Wr]
    const bool is_l = tc < DIM;
    const float* W = is_l ? Wl : Wr;
    const float* b = is_l ? bl : br;
    const int col = is_l ? tc : tc - DIM;
    float4 a0 = {0.f, 0.f, 0.f, 0.f}, a1 = a0, a2 = a0, a3 = a0;
#pragma unroll 4
    for (int k = 0; k < DIM; ++k) {
        const float4 wv = *(const float4*)&W[k * DIM + col];
        const float4 xv = *(const float4*)&xs[k][tn];
        a0.x += xv.x * wv.x; a0.y += xv.x * wv.y; a0.z += xv.x * wv.z; a0.w += xv.x * wv.w;
        a1.x += xv.y * wv.x; a1.y += xv.y * wv.y; a1.z += xv.y * wv.z; a1.w += xv.y * wv.w;
        a2.x += xv.z * wv.x; a2.y += xv.z * wv.y; a2.z += xv.z * wv.z; a2.w += xv.z * wv.w;
        a3.x += xv.w * wv.x; a3.y += xv.w * wv.y; a3.z += xv.w * wv.z; a3.w += xv.w * wv.w;
    }
    const float4 bv = *(const float4*)&b[col];
    a0.x += bv.x; a0.y += bv.y; a0.z += bv.z; a0.w += bv.w;
    a1.x += bv.x; a1.y += bv.y; a1.z += bv.z; a1.w += bv.w;
    a2.x += bv.x; a2.y += bv.y; a2.z += bv.z; a2.w += bv.w;
    a3.x += bv.x; a3.y += bv.y; a3.z += bv.z; a3.w += bv.w;
    float4 acc[4] = {a0, a1, a2, a3};
#pragma unroll
    for (int i = 0; i < 4; ++i) {
        const int gn = node0 + tn + i;
        if (gn >= N_NODES) continue;
        if (is_l) {
            ushort4 u;
            u.x = f2bf(acc[i].x); u.y = f2bf(acc[i].y);
            u.z = f2bf(acc[i].z); u.w = f2bf(acc[i].w);
            *(ushort4*)&xl_bf[(size_t)gn * DIM + col] = u;
        } else {
            *(float4*)&xr[(size_t)gn * DIM + col] = acc[i];
        }
    }
}

// ---------------- CSR build ----------------
__global__ __launch_bounds__(256) void hist_kernel(const int* __restrict__ dst_idx,
                                                   int* __restrict__ cnt) {
    int i = blockIdx.x * 256 + threadIdx.x;
    int e = i * 4;
    if (e + 4 <= N_EDGES) {
        const int4 d4 = *(const int4*)(dst_idx + e);
        atomicAdd(&cnt[d4.x], 1);
        atomicAdd(&cnt[d4.y], 1);
        atomicAdd(&cnt[d4.z], 1);
        atomicAdd(&cnt[d4.w], 1);
    } else {
        for (; e < N_EDGES; ++e) atomicAdd(&cnt[dst_idx[e]], 1);
    }
}

__global__ __launch_bounds__(SCAN_BS) void scan1_kernel(int* __restrict__ cnt,
                                                        int* __restrict__ partials) {
    __shared__ int sh[SCAN_BS];
    const int i = blockIdx.x * SCAN_BS + threadIdx.x;
    const int deg = (i < N_NODES) ? cnt[i] : 0;
    const int v = (deg + 7) & ~7;                      // padded length (%8)
    sh[threadIdx.x] = v;
    __syncthreads();
    for (int off = 1; off < SCAN_BS; off <<= 1) {
        int u = (threadIdx.x >= off) ? sh[threadIdx.x - off] : 0;
        __syncthreads();
        sh[threadIdx.x] += u;
        __syncthreads();
    }
    if (i < N_NODES) cnt[i] = sh[threadIdx.x] - v;     // exclusive padded start
    if (threadIdx.x == SCAN_BS - 1) partials[blockIdx.x] = sh[threadIdx.x];
}

// merged scan2+scan3: every block redundantly scans the 196 partials (cheap),
// then applies its offset and initializes the scatter cursor.
__global__ __launch_bounds__(SCAN_BS) void scan23_kernel(int* __restrict__ cnt,
                                                         const int* __restrict__ partials,
                                                         int* __restrict__ cursor) {
    __shared__ int sh[SCAN_BS];
    const int t = threadIdx.x;
    sh[t] = (t < NB_SCAN) ? partials[t] : 0;
    __syncthreads();
    for (int off = 1; off < SCAN_BS; off <<= 1) {
        int u = (t >= off) ? sh[t - off] : 0;
        __syncthreads();
        sh[t] += u;
        __syncthreads();
    }
    const int boff = (blockIdx.x == 0) ? 0 : sh[blockIdx.x - 1];
    const int i = blockIdx.x * SCAN_BS + t;
    if (i < N_NODES) {
        const int rs = cnt[i] + boff;
        cnt[i] = rs;        // row_start (multiple of 8)
        cursor[i] = rs;     // scatter cursor; becomes real row end
    }
}

// scatter: ONE aligned 16B store per edge: {ea0, ea1, ea2, bitcast(src)}
__global__ __launch_bounds__(256) void scatter_kernel(
    const int* __restrict__ src_idx, const int* __restrict__ dst_idx,
    const float* __restrict__ ea,
    int* __restrict__ cursor, float4* __restrict__ packed) {
    int e = blockIdx.x * 256 + threadIdx.x;
    if (e >= N_EDGES) return;
    int pos = atomicAdd(&cursor[dst_idx[e]], 1);
    float4 p;
    p.x = ea[(size_t)e * 3 + 0];
    p.y = ea[(size_t)e * 3 + 1];
    p.z = ea[(size_t)e * 3 + 2];
    p.w = __int_as_float(src_idx[e]);
    packed[pos] = p;
}

// per-edge logit from decoded xl + constants (2 dims per lane)
#define LOGIT(PX, K, XL0, XL1)                                               \
    {                                                                        \
        float t0 = (XL0) + xrv.x + (K).x * we0.x + (K).y * we1.x + (K).z * we2.x; \
        float t1 = (XL1) + xrv.y + (K).x * we0.y + (K).y * we1.y + (K).z * we2.y; \
        t0 = t0 > 0.f ? t0 : NEG_SLOPE * t0;                                 \
        t1 = t1 > 0.f ? t1 : NEG_SLOPE * t1;                                 \
        PX = t0 * at.x + t1 * at.y;                                          \
    }

// K_F: one wave per 4 consecutive nodes; constants hoisted; 8 edges/iter
// straight-line; interleaved butterfly; deferred-max online softmax; fused LN.
__global__ __launch_bounds__(256) void fused_node_kernel(
    const float* __restrict__ x, const __hip_bfloat16* __restrict__ xl_bf,
    const int* __restrict__ row_start, const int* __restrict__ cursor,
    const float4* __restrict__ packed,
    const float* __restrict__ We, const float* __restrict__ att,
    const float* __restrict__ bias, const float* __restrict__ rw_p,
    const float* __restrict__ gamma, const float* __restrict__ beta,
    float* __restrict__ out)
{
    const int wave = blockIdx.x * 4 + (threadIdx.x >> 6);
    const int lane = threadIdx.x & 63;
    const int v0 = wave * 4;
    if (v0 >= N_NODES) return;
    const int loff = 2 * lane;
    // node-invariant constants (once per wave, amortized over 4 nodes)
    const float2 at  = *(const float2*)&att[loff];
    const float2 we0 = *(const float2*)&We[0 * DIM + loff];
    const float2 we1 = *(const float2*)&We[1 * DIM + loff];
    const float2 we2 = *(const float2*)&We[2 * DIM + loff];
    const float2 bi  = *(const float2*)&bias[loff];
    const float2 gm  = *(const float2*)&gamma[loff];
    const float2 bt  = *(const float2*)&beta[loff];
    const float rw = rw_p[0];

    for (int j = 0; j < 4; ++j) {
        const int v = v0 + j;
        if (v >= N_NODES) return;
        const int begin = row_start[v];      // %8 == 0
        const int end   = cursor[v];         // begin + deg
        const size_t nb = (size_t)v * DIM + loff;
        const float2 xrv = *(const float2*)&out[nb];   // x_r row (parked)

        float m = -3.4e38f, s = 0.f, a0 = 0.f, a1 = 0.f;
        int pos = begin;
        const int full8 = begin + ((end - begin) & ~7);

        for (; pos < full8; pos += 8) {
            const float4 k0 = packed[pos + 0], k1 = packed[pos + 1];
            const float4 k2 = packed[pos + 2], k3 = packed[pos + 3];
            const float4 k4 = packed[pos + 4], k5 = packed[pos + 5];
            const float4 k6 = packed[pos + 6], k7 = packed[pos + 7];
            const unsigned xu0 = *(const unsigned*)&xl_bf[(size_t)__float_as_int(k0.w) * DIM + loff];
            const unsigned xu1 = *(const unsigned*)&xl_bf[(size_t)__float_as_int(k1.w) * DIM + loff];
            const unsigned xu2 = *(const unsigned*)&xl_bf[(size_t)__float_as_int(k2.w) * DIM + loff];
            const unsigned xu3 = *(const unsigned*)&xl_bf[(size_t)__float_as_int(k3.w) * DIM + loff];
            const unsigned xu4 = *(const unsigned*)&xl_bf[(size_t)__float_as_int(k4.w) * DIM + loff];
            const unsigned xu5 = *(const unsigned*)&xl_bf[(size_t)__float_as_int(k5.w) * DIM + loff];
            const unsigned xu6 = *(const unsigned*)&xl_bf[(size_t)__float_as_int(k6.w) * DIM + loff];
            const unsigned xu7 = *(const unsigned*)&xl_bf[(size_t)__float_as_int(k7.w) * DIM + loff];
            const float xl00 = __uint_as_float(xu0 << 16), xl10 = __uint_as_float(xu0 & 0xffff0000u);
            const float xl01 = __uint_as_float(xu1 << 16), xl11 = __uint_as_float(xu1 & 0xffff0000u);
            const float xl02 = __uint_as_float(xu2 << 16), xl12 = __uint_as_float(xu2 & 0xffff0000u);
            const float xl03 = __uint_as_float(xu3 << 16), xl13 = __uint_as_float(xu3 & 0xffff0000u);
            const float xl04 = __uint_as_float(xu4 << 16), xl14 = __uint_as_float(xu4 & 0xffff0000u);
            const float xl05 = __uint_as_float(xu5 << 16), xl15 = __uint_as_float(xu5 & 0xffff0000u);
            const float xl06 = __uint_as_float(xu6 << 16), xl16 = __uint_as_float(xu6 & 0xffff0000u);
            const float xl07 = __uint_as_float(xu7 << 16), xl17 = __uint_as_float(xu7 & 0xffff0000u);

            float P0, P1, P2, P3, P4, P5, P6, P7;
            LOGIT(P0, k0, xl00, xl10)  LOGIT(P1, k1, xl01, xl11)
            LOGIT(P2, k2, xl02, xl12)  LOGIT(P3, k3, xl03, xl13)
            LOGIT(P4, k4, xl04, xl14)  LOGIT(P5, k5, xl05, xl15)
            LOGIT(P6, k6, xl06, xl16)  LOGIT(P7, k7, xl07, xl17)

            const bool b1 = (lane & 1), b2 = (lane & 2), b4 = (lane & 4);
            float A0, A1, A2, A3, B0, B1, G;
            {
                const float q0 = __shfl_xor(P0, 1, 64), q1 = __shfl_xor(P1, 1, 64);
                const float q2 = __shfl_xor(P2, 1, 64), q3 = __shfl_xor(P3, 1, 64);
                const float q4 = __shfl_xor(P4, 1, 64), q5 = __shfl_xor(P5, 1, 64);
                const float q6 = __shfl_xor(P6, 1, 64), q7 = __shfl_xor(P7, 1, 64);
                A0 = b1 ? (P1 + q1) : (P0 + q0);
                A1 = b1 ? (P3 + q3) : (P2 + q2);
                A2 = b1 ? (P5 + q5) : (P4 + q4);
                A3 = b1 ? (P7 + q7) : (P6 + q6);
            }
            {
                const float q0 = __shfl_xor(A0, 2, 64), q1 = __shfl_xor(A1, 2, 64);
                const float q2 = __shfl_xor(A2, 2, 64), q3 = __shfl_xor(A3, 2, 64);
                B0 = b2 ? (A1 + q1) : (A0 + q0);
                B1 = b2 ? (A3 + q3) : (A2 + q2);
            }
            {
                const float q0 = __shfl_xor(B0, 4, 64), q1 = __shfl_xor(B1, 4, 64);
                G = b4 ? (B1 + q1) : (B0 + q0);
            }
            G += __shfl_xor(G, 8, 64);
            G += __shfl_xor(G, 16, 64);
            G += __shfl_xor(G, 32, 64);
            const float p0 = __shfl(G, 0, 64), p1 = __shfl(G, 1, 64);
            const float p2 = __shfl(G, 2, 64), p3 = __shfl(G, 3, 64);
            const float p4 = __shfl(G, 4, 64), p5 = __shfl(G, 5, 64);
            const float p6 = __shfl(G, 6, 64), p7 = __shfl(G, 7, 64);

            const float pm = fmaxf(fmaxf(fmaxf(p0, p1), fmaxf(p2, p3)),
                                   fmaxf(fmaxf(p4, p5), fmaxf(p6, p7)));
            if (pm <= m + 8.f) {
                const float w0 = __expf(p0 - m), w1 = __expf(p1 - m);
                const float w2 = __expf(p2 - m), w3 = __expf(p3 - m);
                const float w4 = __expf(p4 - m), w5 = __expf(p5 - m);
                const float w6 = __expf(p6 - m), w7 = __expf(p7 - m);
                s  += ((w0 + w1) + (w2 + w3)) + ((w4 + w5) + (w6 + w7));
                a0 += (w0 * xl00 + w1 * xl01 + w2 * xl02 + w3 * xl03)
                    + (w4 * xl04 + w5 * xl05 + w6 * xl06 + w7 * xl07);
                a1 += (w0 * xl10 + w1 * xl11 + w2 * xl12 + w3 * xl13)
                    + (w4 * xl14 + w5 * xl15 + w6 * xl16 + w7 * xl17);
            } else {
                const float mn = fmaxf(m, pm);
                const float f  = __expf(m - mn);
                const float w0 = __expf(p0 - mn), w1 = __expf(p1 - mn);
                const float w2 = __expf(p2 - mn), w3 = __expf(p3 - mn);
                const float w4 = __expf(p4 - mn), w5 = __expf(p5 - mn);
                const float w6 = __expf(p6 - mn), w7 = __expf(p7 - mn);
                s  = s  * f + ((w0 + w1) + (w2 + w3)) + ((w4 + w5) + (w6 + w7));
                a0 = a0 * f + (w0 * xl00 + w1 * xl01 + w2 * xl02 + w3 * xl03)
                            + (w4 * xl04 + w5 * xl05 + w6 * xl06 + w7 * xl07);
                a1 = a1 * f + (w0 * xl10 + w1 * xl11 + w2 * xl12 + w3 * xl13)
                            + (w4 * xl14 + w5 * xl15 + w6 * xl16 + w7 * xl17);
                m = mn;
            }
        }

        if (end - pos >= 4) {
            const float4 k0 = packed[pos + 0], k1 = packed[pos + 1];
            const float4 k2 = packed[pos + 2], k3 = packed[pos + 3];
            const unsigned xu0 = *(const unsigned*)&xl_bf[(size_t)__float_as_int(k0.w) * DIM + loff];
            const unsigned xu1 = *(const unsigned*)&xl_bf[(size_t)__float_as_int(k1.w) * DIM + loff];
            const unsigned xu2 = *(const unsigned*)&xl_bf[(size_t)__float_as_int(k2.w) * DIM + loff];
            const unsigned xu3 = *(const unsigned*)&xl_bf[(size_t)__float_as_int(k3.w) * DIM + loff];
            const float xl00 = __uint_as_float(xu0 << 16), xl10 = __uint_as_float(xu0 & 0xffff0000u);
            const float xl01 = __uint_as_float(xu1 << 16), xl11 = __uint_as_float(xu1 & 0xffff0000u);
            const float xl02 = __uint_as_float(xu2 << 16), xl12 = __uint_as_float(xu2 & 0xffff0000u);
            const float xl03 = __uint_as_float(xu3 << 16), xl13 = __uint_as_float(xu3 & 0xffff0000u);
            float P0, P1, P2, P3;
            LOGIT(P0, k0, xl00, xl10)  LOGIT(P1, k1, xl01, xl11)
            LOGIT(P2, k2, xl02, xl12)  LOGIT(P3, k3, xl03, xl13)
            const float tA0 = __shfl_xor(P0, 1, 64), tA1 = __shfl_xor(P1, 1, 64);
            const float tB0 = __shfl_xor(P2, 1, 64), tB1 = __shfl_xor(P3, 1, 64);
            const bool b0 = (lane & 1);
            float A = b0 ? (P1 + tA1) : (P0 + tA0);
            float B = b0 ? (P3 + tB1) : (P2 + tB0);
            const float tA = __shfl_xor(A, 2, 64), tB = __shfl_xor(B, 2, 64);
            float C = (lane & 2) ? (B + tB) : (A + tA);
            C += __shfl_xor(C, 4, 64);
            C += __shfl_xor(C, 8, 64);
            C += __shfl_xor(C, 16, 64);
            C += __shfl_xor(C, 32, 64);
            const float p0 = __shfl(C, 0, 64), p1 = __shfl(C, 1, 64);
            const float p2 = __shfl(C, 2, 64), p3 = __shfl(C, 3, 64);
            const float pm = fmaxf(fmaxf(p0, p1), fmaxf(p2, p3));
            if (pm <= m + 8.f) {
                const float w0 = __expf(p0 - m), w1 = __expf(p1 - m);
                const float w2 = __expf(p2 - m), w3 = __expf(p3 - m);
                s  += (w0 + w1) + (w2 + w3);
                a0 += w0 * xl00 + w1 * xl01 + w2 * xl02 + w3 * xl03;
                a1 += w0 * xl10 + w1 * xl11 + w2 * xl12 + w3 * xl13;
            } else {
                const float mn = fmaxf(m, pm);
                const float f  = __expf(m - mn);
                const float w0 = __expf(p0 - mn), w1 = __expf(p1 - mn);
                const float w2 = __expf(p2 - mn), w3 = __expf(p3 - mn);
                s  = s  * f + (w0 + w1) + (w2 + w3);
                a0 = a0 * f + w0 * xl00 + w1 * xl01 + w2 * xl02 + w3 * xl03;
                a1 = a1 * f + w0 * xl10 + w1 * xl11 + w2 * xl12 + w3 * xl13;
                m = mn;
            }
            pos += 4;
        }

        for (; pos < end; ++pos) {
            const float4 pk = packed[pos];
            const unsigned xu = *(const unsigned*)&xl_bf[(size_t)__float_as_int(pk.w) * DIM + loff];
            const float xl0 = __uint_as_float(xu << 16);
            const float xl1 = __uint_as_float(xu & 0xffff0000u);
            float p;
            LOGIT(p, pk, xl0, xl1)
#pragma unroll
            for (int o = 32; o > 0; o >>= 1) p += __shfl_xor(p, o, 64);
            if (p <= m + 8.f) {
                const float w = __expf(p - m);
                s += w; a0 += w * xl0; a1 += w * xl1;
            } else {
                const float mn = fmaxf(m, p);
                const float f = __expf(m - mn);
                const float w = __expf(p - mn);
                s = s * f + w; a0 = a0 * f + w * xl0; a1 = a1 * f + w * xl1;
                m = mn;
            }
        }

        const float inv = 1.f / (s + 1e-16f);

        // epilogue: residual + LayerNorm
        const float2 xv = *(const float2*)&x[nb];
        float u0 = xv.x + rw * (a0 * inv + bi.x);
        float u1 = xv.y + rw * (a1 * inv + bi.y);
        float sum = u0 + u1;
#pragma unroll
        for (int o = 32; o > 0; o >>= 1) sum += __shfl_xor(sum, o, 64);
        const float mu = sum * (1.f / DIM);
        const float d0 = u0 - mu, d1 = u1 - mu;
        float q = d0 * d0 + d1 * d1;
#pragma unroll
        for (int o = 32; o > 0; o >>= 1) q += __shfl_xor(q, o, 64);
        const float rstd = rsqrtf(q * (1.f / DIM) + LN_EPS);
        float2 r;
        r.x = d0 * rstd * gm.x + bt.x;
        r.y = d1 * rstd * gm.y + bt.y;
        *(float2*)&out[nb] = r;
    }
}

extern "C" void kernel_launch(void* const* d_in, const int* in_sizes, int n_in,
                              void* d_out, int out_size, void* d_ws, size_t ws_size,
                              hipStream_t stream)
{
    const float* x    = (const float*)d_in[0];
    const int*   ei   = (const int*)d_in[1];
    const float* ea   = (const float*)d_in[2];
    const float* Wl   = (const float*)d_in[3];
    const float* bl   = (const float*)d_in[4];
    const float* Wr   = (const float*)d_in[5];
    const float* br   = (const float*)d_in[6];
    const float* We   = (const float*)d_in[7];
    const float* att  = (const float*)d_in[8];
    const float* bias = (const float*)d_in[9];
    const float* rw   = (const float*)d_in[10];
    const float* gmm  = (const float*)d_in[11];
    const float* bta  = (const float*)d_in[12];
    float* out = (float*)d_out;

    const int* src_idx = ei;            // edge_index[0]
    const int* dst_idx = ei + N_EDGES;  // edge_index[1]

    __hip_bfloat16* xl_bf = (__hip_bfloat16*)d_ws;                 // N*D bf16
    float4* packed    = (float4*)(xl_bf + (size_t)N_NODES * DIM);  // PADCAP
    int*   row_start  = (int*)(packed + PADCAP);                   // N
    int*   cursor     = row_start + N_NODES;                       // N
    int*   partials   = cursor + N_NODES;                          // 256

    hipMemsetAsync(row_start, 0, (size_t)N_NODES * sizeof(int), stream);
    hist_kernel<<<(N_EDGES / 4 + 255) / 256, 256, 0, stream>>>(dst_idx, row_start);
    scan1_kernel<<<NB_SCAN, SCAN_BS, 0, stream>>>(row_start, partials);
    scan23_kernel<<<NB_SCAN, SCAN_BS, 0, stream>>>(row_start, partials, cursor);
    scatter_kernel<<<(N_EDGES + 255) / 256, 256, 0, stream>>>(src_idx, dst_idx, ea,
                                                              cursor, packed);
    lin_kernel<<<(N_NODES + 15) / 16, 256, 0, stream>>>(x, Wl, bl, Wr, br, xl_bf, out);
    fused_node_kernel<<<(N_NODES + 15) / 16, 256, 0, stream>>>(x, xl_bf, row_start, cursor,
                                                               packed,
                                                               We, att, bias, rw, gmm, bta, out);
}

// Round 13
// 342.131 us; speedup vs baseline: 1.3026x; 1.0126x over previous
//
#include <hip/hip_runtime.h>
#include <hip/hip_bf16.h>

#define N_NODES 50000
#define DIM 128
#define N_EDGES 800000
#define NEG_SLOPE 0.2f
#define LN_EPS 1e-5f
#define SCAN_BS 256
#define NB_SCAN ((N_NODES + SCAN_BS - 1) / SCAN_BS)   // 196
#define PADCAP (N_EDGES + 7 * N_NODES)   // >= sum(ceil8(deg))
#define LINPAD 20
#define SCAT_BLOCKS ((N_EDGES + 255) / 256)           // 3125
#define LIN_BLOCKS  ((N_NODES + 15) / 16)             // 3125

// Workspace (~31.4 MB):
//   xl_bf     : N*D bf16      (12.8 MB)
//   packed    : PADCAP float4 (18.4 MB) {ea0,ea1,ea2,src_bits} dst-sorted, rows 8-aligned
//   row_start : N int
//   cursor    : N int
//   partials  : 256 int
// x_r (f32) parked in d_out rows until fused kernel overwrites them.

__device__ __forceinline__ unsigned short f2bf(float f) {
    __hip_bfloat16 h = __float2bfloat16(f);
    return *reinterpret_cast<unsigned short*>(&h);
}

// ---------------- CSR build ----------------
__global__ __launch_bounds__(256) void hist_kernel(const int* __restrict__ dst_idx,
                                                   int* __restrict__ cnt) {
    int i = blockIdx.x * 256 + threadIdx.x;
    int e = i * 4;
    if (e + 4 <= N_EDGES) {
        const int4 d4 = *(const int4*)(dst_idx + e);
        atomicAdd(&cnt[d4.x], 1);
        atomicAdd(&cnt[d4.y], 1);
        atomicAdd(&cnt[d4.z], 1);
        atomicAdd(&cnt[d4.w], 1);
    } else {
        for (; e < N_EDGES; ++e) atomicAdd(&cnt[dst_idx[e]], 1);
    }
}

__global__ __launch_bounds__(SCAN_BS) void scan1_kernel(int* __restrict__ cnt,
                                                        int* __restrict__ partials) {
    __shared__ int sh[SCAN_BS];
    const int i = blockIdx.x * SCAN_BS + threadIdx.x;
    const int deg = (i < N_NODES) ? cnt[i] : 0;
    const int v = (deg + 7) & ~7;                      // padded length (%8)
    sh[threadIdx.x] = v;
    __syncthreads();
    for (int off = 1; off < SCAN_BS; off <<= 1) {
        int u = (threadIdx.x >= off) ? sh[threadIdx.x - off] : 0;
        __syncthreads();
        sh[threadIdx.x] += u;
        __syncthreads();
    }
    if (i < N_NODES) cnt[i] = sh[threadIdx.x] - v;     // exclusive padded start
    if (threadIdx.x == SCAN_BS - 1) partials[blockIdx.x] = sh[threadIdx.x];
}

// merged scan2+scan3: every block redundantly scans the 196 partials (cheap),
// then applies its offset and initializes the scatter cursor.
__global__ __launch_bounds__(SCAN_BS) void scan23_kernel(int* __restrict__ cnt,
                                                         const int* __restrict__ partials,
                                                         int* __restrict__ cursor) {
    __shared__ int sh[SCAN_BS];
    const int t = threadIdx.x;
    sh[t] = (t < NB_SCAN) ? partials[t] : 0;
    __syncthreads();
    for (int off = 1; off < SCAN_BS; off <<= 1) {
        int u = (t >= off) ? sh[t - off] : 0;
        __syncthreads();
        sh[t] += u;
        __syncthreads();
    }
    const int boff = (blockIdx.x == 0) ? 0 : sh[blockIdx.x - 1];
    const int i = blockIdx.x * SCAN_BS + t;
    if (i < N_NODES) {
        const int rs = cnt[i] + boff;
        cnt[i] = rs;        // row_start (multiple of 8)
        cursor[i] = rs;     // scatter cursor; becomes real row end
    }
}

// MERGED: blocks [0, SCAT_BLOCKS) run the edge scatter; blocks
// [SCAT_BLOCKS, SCAT_BLOCKS+LIN_BLOCKS) run the x@W_l / x@W_r GEMM.
// The two roles touch disjoint buffers and overlap on the GPU, hiding the
// cheaper one entirely (single-stream graph capture allows no multi-stream).
__global__ __launch_bounds__(256) void lin_scatter_kernel(
    // scatter args
    const int* __restrict__ src_idx, const int* __restrict__ dst_idx,
    const float* __restrict__ ea,
    int* __restrict__ cursor, float4* __restrict__ packed,
    // lin args
    const float* __restrict__ x,
    const float* __restrict__ Wl, const float* __restrict__ bl,
    const float* __restrict__ Wr, const float* __restrict__ br,
    __hip_bfloat16* __restrict__ xl_bf, float* __restrict__ xr)
{
    __shared__ float xs[DIM][LINPAD];   // used by lin role only (10 KiB)
    const int t = threadIdx.x;

    if (blockIdx.x < SCAT_BLOCKS) {
        // ---------------- scatter role ----------------
        const int e = blockIdx.x * 256 + t;
        if (e >= N_EDGES) return;
        const int pos = atomicAdd(&cursor[dst_idx[e]], 1);
        float4 p;
        p.x = ea[(size_t)e * 3 + 0];
        p.y = ea[(size_t)e * 3 + 1];
        p.z = ea[(size_t)e * 3 + 2];
        p.w = __int_as_float(src_idx[e]);
        packed[pos] = p;
        return;
    }

    // ---------------- lin role ----------------
    const int node0 = (blockIdx.x - SCAT_BLOCKS) * 16;
    for (int idx = t; idx < 16 * DIM; idx += 256) {
        const int n = idx >> 7, k = idx & 127;
        const int gn = node0 + n;
        xs[k][n] = (gn < N_NODES) ? x[(size_t)gn * DIM + k] : 0.f;
    }
    __syncthreads();
    const int tn = (t & 3) * 4;          // nodes tn..tn+3
    const int tc = (t >> 2) * 4;         // cols tc..tc+3 of [Wl|Wr]
    const bool is_l = tc < DIM;
    const float* W = is_l ? Wl : Wr;
    const float* b = is_l ? bl : br;
    const int col = is_l ? tc : tc - DIM;
    float4 a0 = {0.f, 0.f, 0.f, 0.f}, a1 = a0, a2 = a0, a3 = a0;
#pragma unroll 4
    for (int k = 0; k < DIM; ++k) {
        const float4 wv = *(const float4*)&W[k * DIM + col];
        const float4 xv = *(const float4*)&xs[k][tn];
        a0.x += xv.x * wv.x; a0.y += xv.x * wv.y; a0.z += xv.x * wv.z; a0.w += xv.x * wv.w;
        a1.x += xv.y * wv.x; a1.y += xv.y * wv.y; a1.z += xv.y * wv.z; a1.w += xv.y * wv.w;
        a2.x += xv.z * wv.x; a2.y += xv.z * wv.y; a2.z += xv.z * wv.z; a2.w += xv.z * wv.w;
        a3.x += xv.w * wv.x; a3.y += xv.w * wv.y; a3.z += xv.w * wv.z; a3.w += xv.w * wv.w;
    }
    const float4 bv = *(const float4*)&b[col];
    a0.x += bv.x; a0.y += bv.y; a0.z += bv.z; a0.w += bv.w;
    a1.x += bv.x; a1.y += bv.y; a1.z += bv.z; a1.w += bv.w;
    a2.x += bv.x; a2.y += bv.y; a2.z += bv.z; a2.w += bv.w;
    a3.x += bv.x; a3.y += bv.y; a3.z += bv.z; a3.w += bv.w;
    float4 acc[4] = {a0, a1, a2, a3};
#pragma unroll
    for (int i = 0; i < 4; ++i) {
        const int gn = node0 + tn + i;
        if (gn >= N_NODES) continue;
        if (is_l) {
            ushort4 u;
            u.x = f2bf(acc[i].x); u.y = f2bf(acc[i].y);
            u.z = f2bf(acc[i].z); u.w = f2bf(acc[i].w);
            *(ushort4*)&xl_bf[(size_t)gn * DIM + col] = u;
        } else {
            *(float4*)&xr[(size_t)gn * DIM + col] = acc[i];
        }
    }
}

// per-edge logit from decoded xl + constants (2 dims per lane)
#define LOGIT(PX, K, XL0, XL1)                                               \
    {                                                                        \
        float t0 = (XL0) + xrv.x + (K).x * we0.x + (K).y * we1.x + (K).z * we2.x; \
        float t1 = (XL1) + xrv.y + (K).x * we0.y + (K).y * we1.y + (K).z * we2.y; \
        t0 = t0 > 0.f ? t0 : NEG_SLOPE * t0;                                 \
        t1 = t1 > 0.f ? t1 : NEG_SLOPE * t1;                                 \
        PX = t0 * at.x + t1 * at.y;                                          \
    }

// K_F: one wave per 4 consecutive nodes; constants hoisted; 8 edges/iter
// straight-line; interleaved butterfly; deferred-max online softmax; fused LN.
__global__ __launch_bounds__(256) void fused_node_kernel(
    const float* __restrict__ x, const __hip_bfloat16* __restrict__ xl_bf,
    const int* __restrict__ row_start, const int* __restrict__ cursor,
    const float4* __restrict__ packed,
    const float* __restrict__ We, const float* __restrict__ att,
    const float* __restrict__ bias, const float* __restrict__ rw_p,
    const float* __restrict__ gamma, const float* __restrict__ beta,
    float* __restrict__ out)
{
    const int wave = blockIdx.x * 4 + (threadIdx.x >> 6);
    const int lane = threadIdx.x & 63;
    const int v0 = wave * 4;
    if (v0 >= N_NODES) return;
    const int loff = 2 * lane;
    const float2 at  = *(const float2*)&att[loff];
    const float2 we0 = *(const float2*)&We[0 * DIM + loff];
    const float2 we1 = *(const float2*)&We[1 * DIM + loff];
    const float2 we2 = *(const float2*)&We[2 * DIM + loff];
    const float2 bi  = *(const float2*)&bias[loff];
    const float2 gm  = *(const float2*)&gamma[loff];
    const float2 bt  = *(const float2*)&beta[loff];
    const float rw = rw_p[0];

    for (int j = 0; j < 4; ++j) {
        const int v = v0 + j;
        if (v >= N_NODES) return;
        const int begin = row_start[v];      // %8 == 0
        const int end   = cursor[v];         // begin + deg
        const size_t nb = (size_t)v * DIM + loff;
        const float2 xrv = *(const float2*)&out[nb];   // x_r row (parked)

        float m = -3.4e38f, s = 0.f, a0 = 0.f, a1 = 0.f;
        int pos = begin;
        const int full8 = begin + ((end - begin) & ~7);

        for (; pos < full8; pos += 8) {
            const float4 k0 = packed[pos + 0], k1 = packed[pos + 1];
            const float4 k2 = packed[pos + 2], k3 = packed[pos + 3];
            const float4 k4 = packed[pos + 4], k5 = packed[pos + 5];
            const float4 k6 = packed[pos + 6], k7 = packed[pos + 7];
            const unsigned xu0 = *(const unsigned*)&xl_bf[(size_t)__float_as_int(k0.w) * DIM + loff];
            const unsigned xu1 = *(const unsigned*)&xl_bf[(size_t)__float_as_int(k1.w) * DIM + loff];
            const unsigned xu2 = *(const unsigned*)&xl_bf[(size_t)__float_as_int(k2.w) * DIM + loff];
            const unsigned xu3 = *(const unsigned*)&xl_bf[(size_t)__float_as_int(k3.w) * DIM + loff];
            const unsigned xu4 = *(const unsigned*)&xl_bf[(size_t)__float_as_int(k4.w) * DIM + loff];
            const unsigned xu5 = *(const unsigned*)&xl_bf[(size_t)__float_as_int(k5.w) * DIM + loff];
            const unsigned xu6 = *(const unsigned*)&xl_bf[(size_t)__float_as_int(k6.w) * DIM + loff];
            const unsigned xu7 = *(const unsigned*)&xl_bf[(size_t)__float_as_int(k7.w) * DIM + loff];
            const float xl00 = __uint_as_float(xu0 << 16), xl10 = __uint_as_float(xu0 & 0xffff0000u);
            const float xl01 = __uint_as_float(xu1 << 16), xl11 = __uint_as_float(xu1 & 0xffff0000u);
            const float xl02 = __uint_as_float(xu2 << 16), xl12 = __uint_as_float(xu2 & 0xffff0000u);
            const float xl03 = __uint_as_float(xu3 << 16), xl13 = __uint_as_float(xu3 & 0xffff0000u);
            const float xl04 = __uint_as_float(xu4 << 16), xl14 = __uint_as_float(xu4 & 0xffff0000u);
            const float xl05 = __uint_as_float(xu5 << 16), xl15 = __uint_as_float(xu5 & 0xffff0000u);
            const float xl06 = __uint_as_float(xu6 << 16), xl16 = __uint_as_float(xu6 & 0xffff0000u);
            const float xl07 = __uint_as_float(xu7 << 16), xl17 = __uint_as_float(xu7 & 0xffff0000u);

            float P0, P1, P2, P3, P4, P5, P6, P7;
            LOGIT(P0, k0, xl00, xl10)  LOGIT(P1, k1, xl01, xl11)
            LOGIT(P2, k2, xl02, xl12)  LOGIT(P3, k3, xl03, xl13)
            LOGIT(P4, k4, xl04, xl14)  LOGIT(P5, k5, xl05, xl15)
            LOGIT(P6, k6, xl06, xl16)  LOGIT(P7, k7, xl07, xl17)

            const bool b1 = (lane & 1), b2 = (lane & 2), b4 = (lane & 4);
            float A0, A1, A2, A3, B0, B1, G;
            {
                const float q0 = __shfl_xor(P0, 1, 64), q1 = __shfl_xor(P1, 1, 64);
                const float q2 = __shfl_xor(P2, 1, 64), q3 = __shfl_xor(P3, 1, 64);
                const float q4 = __shfl_xor(P4, 1, 64), q5 = __shfl_xor(P5, 1, 64);
                const float q6 = __shfl_xor(P6, 1, 64), q7 = __shfl_xor(P7, 1, 64);
                A0 = b1 ? (P1 + q1) : (P0 + q0);
                A1 = b1 ? (P3 + q3) : (P2 + q2);
                A2 = b1 ? (P5 + q5) : (P4 + q4);
                A3 = b1 ? (P7 + q7) : (P6 + q6);
            }
            {
                const float q0 = __shfl_xor(A0, 2, 64), q1 = __shfl_xor(A1, 2, 64);
                const float q2 = __shfl_xor(A2, 2, 64), q3 = __shfl_xor(A3, 2, 64);
                B0 = b2 ? (A1 + q1) : (A0 + q0);
                B1 = b2 ? (A3 + q3) : (A2 + q2);
            }
            {
                const float q0 = __shfl_xor(B0, 4, 64), q1 = __shfl_xor(B1, 4, 64);
                G = b4 ? (B1 + q1) : (B0 + q0);
            }
            G += __shfl_xor(G, 8, 64);
            G += __shfl_xor(G, 16, 64);
            G += __shfl_xor(G, 32, 64);
            const float p0 = __shfl(G, 0, 64), p1 = __shfl(G, 1, 64);
            const float p2 = __shfl(G, 2, 64), p3 = __shfl(G, 3, 64);
            const float p4 = __shfl(G, 4, 64), p5 = __shfl(G, 5, 64);
            const float p6 = __shfl(G, 6, 64), p7 = __shfl(G, 7, 64);

            const float pm = fmaxf(fmaxf(fmaxf(p0, p1), fmaxf(p2, p3)),
                                   fmaxf(fmaxf(p4, p5), fmaxf(p6, p7)));
            if (pm <= m + 8.f) {
                const float w0 = __expf(p0 - m), w1 = __expf(p1 - m);
                const float w2 = __expf(p2 - m), w3 = __expf(p3 - m);
                const float w4 = __expf(p4 - m), w5 = __expf(p5 - m);
                const float w6 = __expf(p6 - m), w7 = __expf(p7 - m);
                s  += ((w0 + w1) + (w2 + w3)) + ((w4 + w5) + (w6 + w7));
                a0 += (w0 * xl00 + w1 * xl01 + w2 * xl02 + w3 * xl03)
                    + (w4 * xl04 + w5 * xl05 + w6 * xl06 + w7 * xl07);
                a1 += (w0 * xl10 + w1 * xl11 + w2 * xl12 + w3 * xl13)
                    + (w4 * xl14 + w5 * xl15 + w6 * xl16 + w7 * xl17);
            } else {
                const float mn = fmaxf(m, pm);
                const float f  = __expf(m - mn);
                const float w0 = __expf(p0 - mn), w1 = __expf(p1 - mn);
                const float w2 = __expf(p2 - mn), w3 = __expf(p3 - mn);
                const float w4 = __expf(p4 - mn), w5 = __expf(p5 - mn);
                const float w6 = __expf(p6 - mn), w7 = __expf(p7 - mn);
                s  = s  * f + ((w0 + w1) + (w2 + w3)) + ((w4 + w5) + (w6 + w7));
                a0 = a0 * f + (w0 * xl00 + w1 * xl01 + w2 * xl02 + w3 * xl03)
                            + (w4 * xl04 + w5 * xl05 + w6 * xl06 + w7 * xl07);
                a1 = a1 * f + (w0 * xl10 + w1 * xl11 + w2 * xl12 + w3 * xl13)
                            + (w4 * xl14 + w5 * xl15 + w6 * xl16 + w7 * xl17);
                m = mn;
            }
        }

        if (end - pos >= 4) {
            const float4 k0 = packed[pos + 0], k1 = packed[pos + 1];
            const float4 k2 = packed[pos + 2], k3 = packed[pos + 3];
            const unsigned xu0 = *(const unsigned*)&xl_bf[(size_t)__float_as_int(k0.w) * DIM + loff];
            const unsigned xu1 = *(const unsigned*)&xl_bf[(size_t)__float_as_int(k1.w) * DIM + loff];
            const unsigned xu2 = *(const unsigned*)&xl_bf[(size_t)__float_as_int(k2.w) * DIM + loff];
            const unsigned xu3 = *(const unsigned*)&xl_bf[(size_t)__float_as_int(k3.w) * DIM + loff];
            const float xl00 = __uint_as_float(xu0 << 16), xl10 = __uint_as_float(xu0 & 0xffff0000u);
            const float xl01 = __uint_as_float(xu1 << 16), xl11 = __uint_as_float(xu1 & 0xffff0000u);
            const float xl02 = __uint_as_float(xu2 << 16), xl12 = __uint_as_float(xu2 & 0xffff0000u);
            const float xl03 = __uint_as_float(xu3 << 16), xl13 = __uint_as_float(xu3 & 0xffff0000u);
            float P0, P1, P2, P3;
            LOGIT(P0, k0, xl00, xl10)  LOGIT(P1, k1, xl01, xl11)
            LOGIT(P2, k2, xl02, xl12)  LOGIT(P3, k3, xl03, xl13)
            const float tA0 = __shfl_xor(P0, 1, 64), tA1 = __shfl_xor(P1, 1, 64);
            const float tB0 = __shfl_xor(P2, 1, 64), tB1 = __shfl_xor(P3, 1, 64);
            const bool b0 = (lane & 1);
            float A = b0 ? (P1 + tA1) : (P0 + tA0);
            float B = b0 ? (P3 + tB1) : (P2 + tB0);
            const float tA = __shfl_xor(A, 2, 64), tB = __shfl_xor(B, 2, 64);
            float C = (lane & 2) ? (B + tB) : (A + tA);
            C += __shfl_xor(C, 4, 64);
            C += __shfl_xor(C, 8, 64);
            C += __shfl_xor(C, 16, 64);
            C += __shfl_xor(C, 32, 64);
            const float p0 = __shfl(C, 0, 64), p1 = __shfl(C, 1, 64);
            const float p2 = __shfl(C, 2, 64), p3 = __shfl(C, 3, 64);
            const float pm = fmaxf(fmaxf(p0, p1), fmaxf(p2, p3));
            if (pm <= m + 8.f) {
                const float w0 = __expf(p0 - m), w1 = __expf(p1 - m);
                const float w2 = __expf(p2 - m), w3 = __expf(p3 - m);
                s  += (w0 + w1) + (w2 + w3);
                a0 += w0 * xl00 + w1 * xl01 + w2 * xl02 + w3 * xl03;
                a1 += w0 * xl10 + w1 * xl11 + w2 * xl12 + w3 * xl13;
            } else {
                const float mn = fmaxf(m, pm);
                const float f  = __expf(m - mn);
                const float w0 = __expf(p0 - mn), w1 = __expf(p1 - mn);
                const float w2 = __expf(p2 - mn), w3 = __expf(p3 - mn);
                s  = s  * f + (w0 + w1) + (w2 + w3);
                a0 = a0 * f + w0 * xl00 + w1 * xl01 + w2 * xl02 + w3 * xl03;
                a1 = a1 * f + w0 * xl10 + w1 * xl11 + w2 * xl12 + w3 * xl13;
                m = mn;
            }
            pos += 4;
        }

        for (; pos < end; ++pos) {
            const float4 pk = packed[pos];
            const unsigned xu = *(const unsigned*)&xl_bf[(size_t)__float_as_int(pk.w) * DIM + loff];
            const float xl0 = __uint_as_float(xu << 16);
            const float xl1 = __uint_as_float(xu & 0xffff0000u);
            float p;
            LOGIT(p, pk, xl0, xl1)
#pragma unroll
            for (int o = 32; o > 0; o >>= 1) p += __shfl_xor(p, o, 64);
            if (p <= m + 8.f) {
                const float w = __expf(p - m);
                s += w; a0 += w * xl0; a1 += w * xl1;
            } else {
                const float mn = fmaxf(m, p);
                const float f = __expf(m - mn);
                const float w = __expf(p - mn);
                s = s * f + w; a0 = a0 * f + w * xl0; a1 = a1 * f + w * xl1;
                m = mn;
            }
        }

        const float inv = 1.f / (s + 1e-16f);

        // epilogue: residual + LayerNorm
        const float2 xv = *(const float2*)&x[nb];
        float u0 = xv.x + rw * (a0 * inv + bi.x);
        float u1 = xv.y + rw * (a1 * inv + bi.y);
        float sum = u0 + u1;
#pragma unroll
        for (int o = 32; o > 0; o >>= 1) sum += __shfl_xor(sum, o, 64);
        const float mu = sum * (1.f / DIM);
        const float d0 = u0 - mu, d1 = u1 - mu;
        float q = d0 * d0 + d1 * d1;
#pragma unroll
        for (int o = 32; o > 0; o >>= 1) q += __shfl_xor(q, o, 64);
        const float rstd = rsqrtf(q * (1.f / DIM) + LN_EPS);
        float2 r;
        r.x = d0 * rstd * gm.x + bt.x;
        r.y = d1 * rstd * gm.y + bt.y;
        *(float2*)&out[nb] = r;
    }
}

extern "C" void kernel_launch(void* const* d_in, const int* in_sizes, int n_in,
                              void* d_out, int out_size, void* d_ws, size_t ws_size,
                              hipStream_t stream)
{
    const float* x    = (const float*)d_in[0];
    const int*   ei   = (const int*)d_in[1];
    const float* ea   = (const float*)d_in[2];
    const float* Wl   = (const float*)d_in[3];
    const float* bl   = (const float*)d_in[4];
    const float* Wr   = (const float*)d_in[5];
    const float* br   = (const float*)d_in[6];
    const float* We   = (const float*)d_in[7];
    const float* att  = (const float*)d_in[8];
    const float* bias = (const float*)d_in[9];
    const float* rw   = (const float*)d_in[10];
    const float* gmm  = (const float*)d_in[11];
    const float* bta  = (const float*)d_in[12];
    float* out = (float*)d_out;

    const int* src_idx = ei;            // edge_index[0]
    const int* dst_idx = ei + N_EDGES;  // edge_index[1]

    __hip_bfloat16* xl_bf = (__hip_bfloat16*)d_ws;                 // N*D bf16
    float4* packed    = (float4*)(xl_bf + (size_t)N_NODES * DIM);  // PADCAP
    int*   row_start  = (int*)(packed + PADCAP);                   // N
    int*   cursor     = row_start + N_NODES;                       // N
    int*   partials   = cursor + N_NODES;                          // 256

    hipMemsetAsync(row_start, 0, (size_t)N_NODES * sizeof(int), stream);
    hist_kernel<<<(N_EDGES / 4 + 255) / 256, 256, 0, stream>>>(dst_idx, row_start);
    scan1_kernel<<<NB_SCAN, SCAN_BS, 0, stream>>>(row_start, partials);
    scan23_kernel<<<NB_SCAN, SCAN_BS, 0, stream>>>(row_start, partials, cursor);
    lin_scatter_kernel<<<SCAT_BLOCKS + LIN_BLOCKS, 256, 0, stream>>>(
        src_idx, dst_idx, ea, cursor, packed,
        x, Wl, bl, Wr, br, xl_bf, out);
    fused_node_kernel<<<(N_NODES + 15) / 16, 256, 0, stream>>>(x, xl_bf, row_start, cursor,
                                                               packed,
                                                               We, att, bias, rw, gmm, bta, out);
}